// Round 9
// baseline (114.913 us; speedup 1.0000x reference)
//
#include <hip/hip_runtime.h>
#include <hip/hip_fp16.h>
#include <math.h>

// CTC loss forward, SINGLE fused kernel v11: DECOUPLED — no producers, no
// LDS w-matrix, no flags. One block of 1024 threads (16 waves) per batch
// element; B=256 = 256 CUs.
//
// v4-v10 lesson: five producer micro-theories (ILP, MLP, LDS-pipe, hazards,
// prefetch x2) nulled or regressed; prep measures ~6x its pipe arithmetic.
// => the producer->consumer handoff STRUCTURE is the suspect.
// Algebraic key: softmax denominator CANCELS in w = exp(x_lab - x_blank).
// Full-row sums are needed only for cum_b = sum_t [x_blank - lse(t)] — an
// order-free reduction. So:
//   waves 2..15: pure streaming cum_b reduction (depth-2 ping-pong, no
//                ordering, partials -> ps[14]).
//   wave 0 / 1 : fwd / bwd chains SELF-FEED: per chunk 8 per-lane gathers
//                y_pred[b,t,lab_l] + 1 blank-vector load, software-pipelined
//                3 chunks ahead in a STATIC 4-slot ring (rule #20). w in f32
//                (drops fp16 pack; slightly more accurate), computed off the
//                critical path. Chain math identical to v8/v9.
//   one __syncthreads() then wave 0 combines (f64 dot, v7-proven).
// B=256, T=512, C=128 (blank=127), L=64, S=129.

constexpr int Cc = 128;
constexpr int Tt = 512;
constexpr int Ll = 64;
constexpr float INV_LN2 = 1.4426950408889634f;
constexpr float LN2_F   = 0.6931471805599453f;
constexpr float RENORM_THR = 16777216.0f;   // 2^24

__device__ __forceinline__ float fexp2(float x) { return __builtin_amdgcn_exp2f(x); }
__device__ __forceinline__ float flog2(float x) { return __builtin_amdgcn_logf(x); }

template<int CTRL, bool BC>
__device__ __forceinline__ float dppf(float old, float x) {
    return __int_as_float(__builtin_amdgcn_update_dpp(
        __float_as_int(old), __float_as_int(x), CTRL, 0xF, 0xF, BC));
}
// lane i <- lane i-1; lane 0 <- fill. (silicon-proven r3-r7)
__device__ __forceinline__ float wshr1(float x, float fill) { return dppf<0x138, false>(fill, x); }
// lane i <- lane i+1; lane 63 <- fill. (proven v7)
__device__ __forceinline__ float wshl1(float x, float fill) { return dppf<0x130, false>(fill, x); }

__device__ __forceinline__ float rlf(float v, int lane) {
    return __int_as_float(__builtin_amdgcn_readlane(__float_as_int(v), lane));
}
// Row-local (16-lane) reduce (proven r6/r7)
__device__ __forceinline__ float rowsum(float e) {
    e += dppf<0x111, true>(0.f, e);
    e += dppf<0x112, true>(0.f, e);
    e += dppf<0x114, true>(0.f, e);
    e += dppf<0x118, true>(0.f, e);
    return e;
}
// full 64-lane sum landing in lane 63 (proven v10)
__device__ __forceinline__ float sum64_l63(float e) {
    e = rowsum(e);
    e += dppf<0x142, true>(0.f, e);   // row_bcast15
    e += dppf<0x143, true>(0.f, e);   // row_bcast31
    return e;
}
// all-lane wave max via butterfly shuffles (rare renorm path)
__device__ __forceinline__ float xmax64(float m) {
    m = fmaxf(m, __shfl_xor(m, 32, 64));
    m = fmaxf(m, __shfl_xor(m, 16, 64));
    m = fmaxf(m, __shfl_xor(m,  8, 64));
    m = fmaxf(m, __shfl_xor(m,  4, 64));
    m = fmaxf(m, __shfl_xor(m,  2, 64));
    m = fmaxf(m, __shfl_xor(m,  1, 64));
    return m;
}
// double butterfly-xor shuffle (two 32-bit halves) (proven v7)
__device__ __forceinline__ double shflx_d(double v, int mask) {
    const long long x = __double_as_longlong(v);
    int lo = (int)(x & 0xffffffffLL), hi = (int)(x >> 32);
    lo = __shfl_xor(lo, mask, 64);
    hi = __shfl_xor(hi, mask, 64);
    return __longlong_as_double(((long long)hi << 32) | (unsigned)(unsigned int)lo);
}

// ---- forward: 8 full steps + CONDITIONAL renorm (v8-proven, f32 w) ----
__device__ __forceinline__ void do_chunk_f(const float (&dv)[8], float skf,
                                           float& aO, float& aE, float& r0, float& Rtot)
{
    float sd[8];
#pragma unroll
    for (int j = 0; j < 8; ++j) sd[j] = skf * dv[j];
#pragma unroll
    for (int j = 0; j < 8; ++j) {
        const float ad = aO * dv[j];
        const float pE = wshr1(aE, r0);
        const float pO = wshr1(aO, 0.0f);
        const float nO = fmaf(pE, dv[j], fmaf(pO, sd[j], ad));
        aE += aO;
        aO = nO;
    }
    const float mx = fmaxf(fmaxf(aO, aE), r0);
    if (__any(mx >= RENORM_THR)) {
        const float M_ = xmax64(mx);
        int R_ = (int)(__float_as_uint(M_) >> 23) - 127;
        R_ = (R_ < 0) ? 0 : ((R_ > 126) ? 126 : R_);
        const float sc = __uint_as_float((unsigned)(127 - R_) << 23);
        aO = fminf(aO * sc, 4.0f);
        aE = fminf(aE * sc, 4.0f);
        r0 = fminf(r0 * sc, 4.0f);
        Rtot += (float)R_;
    }
}

// ---- backward (transpose), j descending, CONDITIONAL renorm (v8-proven) ----
template<bool GUARD>
__device__ __forceinline__ void do_chunk_b(const float (&dv)[8], int t0, int inlen,
                                           float skfb, float& bO, float& bE,
                                           float& br, float& Rb, int l)
{
#pragma unroll
    for (int j = 7; j >= 0; --j) {
        if (!GUARD || (t0 + j < inlen)) {
            const float BOw = bO * dv[j];
            const float uO  = wshl1(BOw, 0.0f);
            const float t1  = bE + BOw;
            bE += uO;
            br += BOw;
            bO  = fmaf(skfb, uO, t1);
        }
    }
    const float brm = (l == 0) ? br : 0.0f;
    const float mx = fmaxf(fmaxf(bO, bE), brm);
    if (__any(mx >= RENORM_THR)) {
        const float M_ = xmax64(mx);
        int R_ = (int)(__float_as_uint(M_) >> 23) - 127;
        R_ = (R_ < 0) ? 0 : ((R_ > 126) ? 126 : R_);
        const float sc = __uint_as_float((unsigned)(127 - R_) << 23);
        bO = bO * sc;
        bE = bE * sc;
        br = br * sc;
        Rb += (float)R_;
    }
}

__global__ __launch_bounds__(1024, 4) void ctc_fused11_kernel(
    const int* __restrict__ y_true,      // [B, 64]
    const float* __restrict__ y_pred,    // [B, T, C]
    const int* __restrict__ in_len,      // [B]
    const int* __restrict__ lab_len,     // [B]
    float* __restrict__ out)             // [B]
{
    __shared__ float ps[14];             // per-reduction-wave blank partials (log2)
    __shared__ float bstate[130];        // bE[64], bO[64], br0, Rb

    const int b   = blockIdx.x;
    const int tid = threadIdx.x;
    const int w   = tid >> 6;            // wave 0..15
    const int l   = tid & 63;

    int inlen = in_len[b]; if (inlen < 1) inlen = 1; if (inlen > Tt) inlen = Tt;
    int LLv   = lab_len[b]; if (LLv < 1) LLv = 1; if (LLv > Ll) LLv = Ll;

    const int nct  = (inlen + 7) >> 3;   // total chunks (>= 32)
    const int nchf = nct >> 1;           // forward chunks [0, nchf)
    const int nchb = nct - nchf;         // backward chunks [nchf, nct), top-down

    const int lab = y_true[b * Ll + l] & 127;
    const float* rowbase = y_pred + (size_t)b * Tt * Cc;

    // skip-transition mask (lattice lane l vs l-1), needed by both chains
    const int labp = __shfl_up(lab, 1, 64);
    const float skf = ((l >= 1) && (lab != labp)) ? 1.0f : 0.0f;
    const bool live = (l < LLv);

    if (w >= 2) {
        // -------- reduction waves: cum_b = sum_t<inlen [x_blank - lse(t)] -------
        // rows r = wv*4 + q + 56*g, q<4, g<10 (covers [0,512) exactly once).
        // depth-2 ping-pong (v5-pattern: copy out, overwrite slot with g+2).
        const int wv = w - 2;
        float acc = 0.0f;
        float2 A[4], Bb[4];
        auto loadg = [&](int g, float2 (&buf)[4]) {
#pragma unroll
            for (int q = 0; q < 4; ++q) {
                const int r  = wv * 4 + q + 56 * g;
                const int rc = (r < inlen) ? r : 0;          // clamp: legal
                buf[q] = ((const float2*)(rowbase + (size_t)rc * Cc))[l];
            }
        };
        auto procg = [&](int g, float2 (&buf)[4]) {
            float prod = 1.0f, bsum = 0.0f;
#pragma unroll
            for (int q = 0; q < 4; ++q) {
                const float2 v = buf[q];
                {   // prefetch group g+2 into same slot
                    const int r  = wv * 4 + q + 56 * (g + 2);
                    const int rc = (r < inlen) ? r : 0;
                    buf[q] = ((const float2*)(rowbase + (size_t)rc * Cc))[l];
                }
                const int r = wv * 4 + q + 56 * g;
                float e = fexp2(v.x * INV_LN2) + fexp2(v.y * INV_LN2);
                e = sum64_l63(e);
                const float s  = rlf(e, 63);
                const float bl = rlf(v.y, 63);   // class 127 logit
                const bool ok = r < inlen;
                prod *= ok ? s : 1.0f;
                bsum += ok ? bl : 0.0f;
            }
            acc = fmaf(bsum, INV_LN2, acc) - flog2(prod);
        };
        loadg(0, A); loadg(1, Bb);
        for (int g = 0; g < 10; g += 2) { procg(g, A); procg(g + 1, Bb); }
        if (l == 0) ps[wv] = acc;
    } else if (w == 1) {
        // -------- backward chain: self-feeding gathers, 4-slot static ring ------
        const float skfb = __shfl(skf, (l + 1) & 63, 64);
        float bE = (l == LLv - 1) ? 1.0f : 0.0f;
        float bO = bE;
        float br = 0.0f, Rb = 0.0f;
        const int nch = nchb;

        float X0[8], X1[8], X2[8], X3[8];
        float V0, V1, V2, V3;
        auto issue = [&](int k, float (&X)[8], float& BV) {
            const int cc = (k < nch) ? k : (nch - 1);        // clamp: legal
            const int row0 = (nct - 1 - cc) * 8;
#pragma unroll
            for (int j = 0; j < 8; ++j)
                X[j] = rowbase[(size_t)(row0 + j) * Cc + lab];
            BV = rowbase[(size_t)(row0 + (l & 7)) * Cc + 127];
        };
        auto compute = [&](int k, float (&X)[8], float& BV) {
            if (k >= nch) return;
            float dv[8];
#pragma unroll
            for (int j = 0; j < 8; ++j) {
                const float bl = __shfl(BV, j, 64);
                const float ww = fminf(fmaxf(fexp2((X[j] - bl) * INV_LN2),
                                             6.1e-5f), 8192.0f);
                dv[j] = live ? ww : 0.0f;
            }
            const int t0 = (nct - 1 - k) * 8;
            if (t0 + 8 <= inlen) do_chunk_b<false>(dv, t0, inlen, skfb, bO, bE, br, Rb, l);
            else                 do_chunk_b<true >(dv, t0, inlen, skfb, bO, bE, br, Rb, l);
        };
        issue(0, X0, V0); issue(1, X1, V1); issue(2, X2, V2);
        for (int k = 0; k < nch; k += 4) {
            issue(k + 3, X3, V3); compute(k + 0, X0, V0);
            issue(k + 4, X0, V0); compute(k + 1, X1, V1);
            issue(k + 5, X1, V1); compute(k + 2, X2, V2);
            issue(k + 6, X2, V2); compute(k + 3, X3, V3);
        }
        bstate[l]      = bE;
        bstate[64 + l] = bO;
        if (l == 0) { bstate[128] = br; bstate[129] = Rb; }
    }
    // w == 0 (forward chain) handled below so its state stays in registers
    float aO = 0.0f, aE = 0.0f, r0 = 1.0f, Rf = 0.0f;
    if (w == 0) {
        const int nch = nchf;
        float X0[8], X1[8], X2[8], X3[8];
        float V0, V1, V2, V3;
        auto issue = [&](int k, float (&X)[8], float& BV) {
            const int cc = (k < nch) ? k : (nch - 1);
            const int row0 = cc * 8;
#pragma unroll
            for (int j = 0; j < 8; ++j)
                X[j] = rowbase[(size_t)(row0 + j) * Cc + lab];
            BV = rowbase[(size_t)(row0 + (l & 7)) * Cc + 127];
        };
        auto compute = [&](int k, float (&X)[8], float& BV) {
            if (k >= nch) return;
            float dv[8];
#pragma unroll
            for (int j = 0; j < 8; ++j) {
                const float bl = __shfl(BV, j, 64);
                const float ww = fminf(fmaxf(fexp2((X[j] - bl) * INV_LN2),
                                             6.1e-5f), 8192.0f);
                dv[j] = live ? ww : 0.0f;
            }
            do_chunk_f(dv, skf, aO, aE, r0, Rf);   // fwd chunks always full
        };
        issue(0, X0, V0); issue(1, X1, V1); issue(2, X2, V2);
        for (int k = 0; k < nch; k += 4) {
            issue(k + 3, X3, V3); compute(k + 0, X0, V0);
            issue(k + 4, X0, V0); compute(k + 1, X1, V1);
            issue(k + 5, X1, V1); compute(k + 2, X2, V2);
            issue(k + 6, X2, V2); compute(k + 3, X3, V3);
        }
    }

    __syncthreads();   // reductions done, bstate published

    if (w == 0) {
        // ---------------- combine (wave 0): f64 meeting-point dot ---------------
        float cum_b = 0.0f;
#pragma unroll
        for (int q = 0; q < 14; ++q) cum_b += ps[q];

        const float bEl = bstate[l], bOl = bstate[64 + l];
        const float br0 = bstate[128], Rb = bstate[129];
        double cd = (double)aE * (double)bEl + (double)aO * (double)bOl;
        if (l == 0) cd += (double)r0 * (double)br0;
#pragma unroll
        for (int mk = 1; mk < 64; mk <<= 1) cd += shflx_d(cd, mk);
        double sd_ = cd > 1e-300 ? cd : 1e-300;
        const long long u = __double_as_longlong(sd_);
        const int e2 = (int)((u >> 52) & 0x7ff) - 1023;
        const double mant = __longlong_as_double((u & 0xfffffffffffffLL) | 0x3ff0000000000000LL);
        const float l2s = (float)e2 + flog2((float)mant);
        if (l == 0)
            out[b] = -LN2_F * (l2s + Rf + Rb + cum_b);
    }
}

extern "C" void kernel_launch(void* const* d_in, const int* in_sizes, int n_in,
                              void* d_out, int out_size, void* d_ws, size_t ws_size,
                              hipStream_t stream) {
    const int*   y_true  = (const int*)d_in[0];    // [256,64]
    const float* y_pred  = (const float*)d_in[1];  // [256,512,128]
    const int*   in_len  = (const int*)d_in[2];    // [256]
    const int*   lab_len = (const int*)d_in[3];    // [256]
    float*       out     = (float*)d_out;          // [256]
    (void)d_ws; (void)ws_size;

    ctc_fused11_kernel<<<256, 1024, 0, stream>>>(y_true, y_pred, in_len, lab_len, out);
}

// Round 11
// 114.295 us; speedup vs baseline: 1.0054x; 1.0054x over previous
//
#include <hip/hip_runtime.h>
#include <hip/hip_fp16.h>
#include <math.h>

// CTC loss forward v13: the v12 TLP experiment (2 blocks per batch element
// = 32 waves/CU vs the 16 all prior versions ran), HARDENED after the v12
// container failure:
//  - NO atomics / NO per-launch memset / NO cross-block spin: the combine is
//    a tiny SECOND KERNEL on the same stream (stream order = visibility).
//  - ws_size GUARD: if d_ws < payload, launch the known-good v9 fallback
//    (108.6us, passed twice) instead of writing out of bounds (the probable
//    v12 crash: ~270KB payload stored without checking ws_size).
//  - payload writes are plain global stores.
// Theory unchanged: ~80% stall, no pipe saturated, VALUBusy ~= issue
// arithmetic -> latency/TLP bound; waves/CU is the one untouched lever.
// grid 512: block (b,dir) = v9's proven producer->LDS->chain machinery on
// half the time axis; __launch_bounds__(1024,8) caps VGPR at 64 so 2 blocks
// co-reside (LDS 32KB/block). B=256, T=512, C=128 (blank=127), L=64, S=129.

constexpr int Cc = 128;
constexpr int Tt = 512;
constexpr int Ll = 64;
constexpr float INV_LN2 = 1.4426950408889634f;
constexpr float LN2_F   = 0.6931471805599453f;
constexpr float RENORM_THR = 16777216.0f;   // 2^24
constexpr int PAYSTRIDE = 132;              // floats per (b,dir) payload slot

__device__ __forceinline__ float fexp2(float x) { return __builtin_amdgcn_exp2f(x); }
__device__ __forceinline__ float flog2(float x) { return __builtin_amdgcn_logf(x); }

template<int CTRL, bool BC>
__device__ __forceinline__ float dppf(float old, float x) {
    return __int_as_float(__builtin_amdgcn_update_dpp(
        __float_as_int(old), __float_as_int(x), CTRL, 0xF, 0xF, BC));
}
// lane i <- lane i-1; lane 0 <- fill. (silicon-proven r3-r7)
__device__ __forceinline__ float wshr1(float x, float fill) { return dppf<0x138, false>(fill, x); }
// lane i <- lane i+1; lane 63 <- fill. (proven v7)
__device__ __forceinline__ float wshl1(float x, float fill) { return dppf<0x130, false>(fill, x); }

__device__ __forceinline__ float rlf(float v, int lane) {
    return __int_as_float(__builtin_amdgcn_readlane(__float_as_int(v), lane));
}
// Row-local (16-lane) reduce (proven r6/r7)
__device__ __forceinline__ float rowsum(float e) {
    e += dppf<0x111, true>(0.f, e);
    e += dppf<0x112, true>(0.f, e);
    e += dppf<0x114, true>(0.f, e);
    e += dppf<0x118, true>(0.f, e);
    return e;
}
// all-lane wave max via butterfly shuffles (rare renorm path, v8-proven)
__device__ __forceinline__ float xmax64(float m) {
    m = fmaxf(m, __shfl_xor(m, 32, 64));
    m = fmaxf(m, __shfl_xor(m, 16, 64));
    m = fmaxf(m, __shfl_xor(m,  8, 64));
    m = fmaxf(m, __shfl_xor(m,  4, 64));
    m = fmaxf(m, __shfl_xor(m,  2, 64));
    m = fmaxf(m, __shfl_xor(m,  1, 64));
    return m;
}
__device__ __forceinline__ float bperm_f(int srclane, float v) {
    return __int_as_float(__builtin_amdgcn_ds_bpermute(srclane << 2, __float_as_int(v)));
}
// double butterfly-xor shuffle (two 32-bit halves) (proven v7)
__device__ __forceinline__ double shflx_d(double v, int mask) {
    const long long x = __double_as_longlong(v);
    int lo = (int)(x & 0xffffffffLL), hi = (int)(x >> 32);
    lo = __shfl_xor(lo, mask, 64);
    hi = __shfl_xor(hi, mask, 64);
    return __longlong_as_double(((long long)hi << 32) | (unsigned)(unsigned int)lo);
}

__device__ __forceinline__ void unpack8(uint4 raw, float (&dv)[8]) {
    const __half2 h0 = *reinterpret_cast<const __half2*>(&raw.x);
    const __half2 h1 = *reinterpret_cast<const __half2*>(&raw.y);
    const __half2 h2 = *reinterpret_cast<const __half2*>(&raw.z);
    const __half2 h3 = *reinterpret_cast<const __half2*>(&raw.w);
    dv[0] = __low2float(h0); dv[1] = __high2float(h0);
    dv[2] = __low2float(h1); dv[3] = __high2float(h1);
    dv[4] = __low2float(h2); dv[5] = __high2float(h2);
    dv[6] = __low2float(h3); dv[7] = __high2float(h3);
}

// ---- forward: 8 full steps + CONDITIONAL renorm (v8/v9-proven) ----
__device__ __forceinline__ void do_chunk_f(uint4 raw, float skf,
                                           float& aO, float& aE, float& r0, float& Rtot)
{
    float dv[8]; unpack8(raw, dv);
    float sd[8];
#pragma unroll
    for (int j = 0; j < 8; ++j) sd[j] = skf * dv[j];
#pragma unroll
    for (int j = 0; j < 8; ++j) {
        const float ad = aO * dv[j];
        const float pE = wshr1(aE, r0);
        const float pO = wshr1(aO, 0.0f);
        const float nO = fmaf(pE, dv[j], fmaf(pO, sd[j], ad));
        aE += aO;
        aO = nO;
    }
    const float mx = fmaxf(fmaxf(aO, aE), r0);
    if (__any(mx >= RENORM_THR)) {
        const float M_ = xmax64(mx);
        int R_ = (int)(__float_as_uint(M_) >> 23) - 127;
        R_ = (R_ < 0) ? 0 : ((R_ > 126) ? 126 : R_);
        const float sc = __uint_as_float((unsigned)(127 - R_) << 23);
        aO = fminf(aO * sc, 4.0f);
        aE = fminf(aE * sc, 4.0f);
        r0 = fminf(r0 * sc, 4.0f);
        Rtot += (float)R_;
    }
}

// ---- backward (transpose), j descending, CONDITIONAL renorm (v8/v9-proven) ----
template<bool GUARD>
__device__ __forceinline__ void do_chunk_b(uint4 raw, int t0, int inlen, float skfb,
                                           float& bO, float& bE, float& br, float& Rb,
                                           int l)
{
    float dv[8]; unpack8(raw, dv);
#pragma unroll
    for (int j = 7; j >= 0; --j) {
        if (!GUARD || (t0 + j < inlen)) {
            const float BOw = bO * dv[j];
            const float uO  = wshl1(BOw, 0.0f);
            const float t1  = bE + BOw;
            bE += uO;
            br += BOw;
            bO  = fmaf(skfb, uO, t1);
        }
    }
    const float brm = (l == 0) ? br : 0.0f;
    const float mx = fmaxf(fmaxf(bO, bE), brm);
    if (__any(mx >= RENORM_THR)) {
        const float M_ = xmax64(mx);
        int R_ = (int)(__float_as_uint(M_) >> 23) - 127;
        R_ = (R_ < 0) ? 0 : ((R_ > 126) ? 126 : R_);
        const float sc = __uint_as_float((unsigned)(127 - R_) << 23);
        bO = bO * sc;
        bE = bE * sc;
        br = br * sc;
        Rb += (float)R_;
    }
}

// ===================== v13 half kernel (grid 512, TLP x2) =====================
__global__ __launch_bounds__(1024, 8) void ctc_half_kernel(
    const int* __restrict__ y_true,      // [B, 64]
    const float* __restrict__ y_pred,    // [B, T, C]
    const int* __restrict__ in_len,      // [B]
    const int* __restrict__ lab_len,     // [B]
    float* __restrict__ pay)             // [B][2][PAYSTRIDE]
{
    constexpr int NPSH = 15;             // producers (waves 1..15)
    constexpr int NRDH = 3;              // ceil(32/15) flag rounds
    __shared__ __half w_lds[32][64][8];  // [side-chunk k][lane][t&7], 32 KB
    __shared__ float  ps[NPSH];
    __shared__ int    ctr[NRDH];

    const int dir = blockIdx.x & 1;      // 0 = forward side, 1 = backward side
    const int b   = blockIdx.x >> 1;
    const int tid = threadIdx.x;
    const int w   = tid >> 6;
    const int l   = tid & 63;

    if (tid < NRDH) ctr[tid] = 0;
    __syncthreads();

    int inlen = in_len[b]; if (inlen < 1) inlen = 1; if (inlen > Tt) inlen = Tt;
    int LLv   = lab_len[b]; if (LLv < 1) LLv = 1; if (LLv > Ll) LLv = Ll;

    const int nct   = (inlen + 7) >> 3;
    const int nchf  = nct >> 1;
    const int nchb  = nct - nchf;
    const int nside = dir ? nchb : nchf; // <= 32

    const int lab = y_true[b * Ll + l] & 127;
    const float* rowbase = y_pred + (size_t)b * Tt * Cc;

    const int labp = __shfl_up(lab, 1, 64);
    const float skf = ((l >= 1) && (lab != labp)) ? 1.0f : 0.0f;
    const bool live = (l < LLv);

    float stE = 0.0f, stO = 0.0f, stX = 0.0f, stR = 0.0f;

    if (w >= 1) {
        // ---- producers (v9-proven body), k = side-order index ----
        const int pw = w - 1;
        const int glane = lab >> 1;
        const int lsel  = lab & 1;
        float acc = 0.0f;

        for (int k = pw, idx = 0; k < nside; k += NPSH, ++idx) {
            const int c = dir ? (nct - 1 - k) : k;
            const int row0 = c * 8;
            float2 rv[8];
#pragma unroll
            for (int t = 0; t < 8; ++t)
                rv[t] = ((const float2*)(rowbase + (size_t)(row0 + t) * Cc))[l];

            float prod = 1.0f, bsum = 0.0f;
            uint4 pk;
            auto wbits = [&](int t) -> unsigned {
                const float2 v = rv[t];
                float e = fexp2(v.x * INV_LN2) + fexp2(v.y * INV_LN2);
                e = rowsum(e);
                const float s  = (rlf(e, 15) + rlf(e, 31)) + (rlf(e, 47) + rlf(e, 63));
                const float bl = rlf(v.y, 63);       // class 127 logit
                const bool ok = (row0 + t) < inlen;
                prod *= ok ? s : 1.0f;
                bsum += ok ? bl : 0.0f;
                const float xa = bperm_f(glane, v.x);
                const float xb = bperm_f(glane, v.y);
                const float xl = lsel ? xb : xa;
                float ww = fminf(fmaxf(fexp2((xl - bl) * INV_LN2), 6.1e-5f), 8192.0f);
                ww = live ? ww : 0.0f;
                return (unsigned)__half_as_ushort(__float2half(ww));
            };
            pk.x = wbits(0) | (wbits(1) << 16);
            pk.y = wbits(2) | (wbits(3) << 16);
            pk.z = wbits(4) | (wbits(5) << 16);
            pk.w = wbits(6) | (wbits(7) << 16);

            acc = fmaf(bsum, INV_LN2, acc) - flog2(prod);
            *(uint4*)&w_lds[k][l][0] = pk;
            asm volatile("s_waitcnt lgkmcnt(0)" ::: "memory");
            if (l == 0) atomicAdd(&ctr[idx], 1);     // LDS atomic (intra-block)
        }
        if (l == 0) ps[pw] = acc;
    } else {
        // ---- chain (wave 0), consumes side-chunks in order ----
        volatile int* vc = ctr;
        int ready = 0, rr = 0;
        auto wait_k = [&](int kneed) {
            while (ready <= kneed) {
                const int rem  = nside - rr * NPSH;
                const int need = rem < NPSH ? rem : NPSH;
                if (vc[rr] >= need) { ready += need; ++rr; }
                else __builtin_amdgcn_s_sleep(1);
            }
            asm volatile("" ::: "memory");
        };

        if (dir == 0) {
            float aO = 0.0f, aE = 0.0f, r0 = 1.0f, Rf = 0.0f;
            if (nside > 0) {
                wait_k(0);
                uint4 A = *(const uint4*)&w_lds[0][l][0];
                for (int k = 0; k < nside; ++k) {
                    uint4 Bv = A;
                    if (k + 1 < nside) { wait_k(k + 1); Bv = *(const uint4*)&w_lds[k + 1][l][0]; }
                    do_chunk_f(A, skf, aO, aE, r0, Rf);   // fwd chunks always full
                    A = Bv;
                }
            }
            stE = aE; stO = aO; stX = r0; stR = Rf;
        } else {
            const float skfb = __shfl(skf, (l + 1) & 63, 64);
            float bE = (l == LLv - 1) ? 1.0f : 0.0f;
            float bO = bE;
            float br = 0.0f, Rb = 0.0f;
            if (nside > 0) {
                wait_k(0);
                uint4 A = *(const uint4*)&w_lds[0][l][0];
                for (int k = 0; k < nside; ++k) {
                    uint4 Bv = A;
                    if (k + 1 < nside) { wait_k(k + 1); Bv = *(const uint4*)&w_lds[k + 1][l][0]; }
                    const int t0 = (nct - 1 - k) * 8;
                    if (t0 + 8 <= inlen) do_chunk_b<false>(A, t0, inlen, skfb, bO, bE, br, Rb, l);
                    else                 do_chunk_b<true >(A, t0, inlen, skfb, bO, bE, br, Rb, l);
                    A = Bv;
                }
            }
            stE = bE; stO = bO; stX = br; stR = Rb;
        }
    }

    __syncthreads();   // ps[] complete; chain state in wave-0 regs

    if (w == 0) {
        float cumb = 0.0f;
#pragma unroll
        for (int q = 0; q < NPSH; ++q) cumb += ps[q];
        float* mine = pay + (size_t)(b * 2 + dir) * PAYSTRIDE;
        mine[l]      = stE;              // plain stores; next-kernel visibility
        mine[64 + l] = stO;              // guaranteed by stream ordering
        if (l == 0) { mine[128] = stX; mine[129] = stR; mine[130] = cumb; }
    }
}

// ===================== v13 combine kernel (grid 256 x 64) =====================
__global__ void ctc_combine_kernel(const float* __restrict__ pay,
                                   float* __restrict__ out)
{
    const int b = blockIdx.x;
    const int l = threadIdx.x;           // one wave
    const float* fs = pay + (size_t)(b * 2 + 0) * PAYSTRIDE;
    const float* bs = pay + (size_t)(b * 2 + 1) * PAYSTRIDE;
    const float aE = fs[l], aO = fs[64 + l];
    const float r0 = fs[128], Rf = fs[129], cbf = fs[130];
    const float bE = bs[l], bO = bs[64 + l];
    const float br = bs[128], Rb = bs[129], cbb = bs[130];

    double cd = (double)aE * (double)bE + (double)aO * (double)bO;
    if (l == 0) cd += (double)r0 * (double)br;
#pragma unroll
    for (int mk = 1; mk < 64; mk <<= 1) cd += shflx_d(cd, mk);
    double sd_ = cd > 1e-300 ? cd : 1e-300;
    const long long u = __double_as_longlong(sd_);
    const int e2 = (int)((u >> 52) & 0x7ff) - 1023;
    const double mant = __longlong_as_double((u & 0xfffffffffffffLL) | 0x3ff0000000000000LL);
    const float l2s = (float)e2 + flog2((float)mant);
    if (l == 0)
        out[b] = -LN2_F * (l2s + Rf + Rb + cbf + cbb);
}

// ============ fallback: v9 kernel verbatim (known-good, 108.6us) =============
__global__ __launch_bounds__(1024, 1) void ctc_fb_kernel(
    const int* __restrict__ y_true, const float* __restrict__ y_pred,
    const int* __restrict__ in_len, const int* __restrict__ lab_len,
    float* __restrict__ out)
{
    constexpr int NPS = 7;
    __shared__ __half w_lds[Tt / 8][64][8];
    __shared__ float  ps[2 * NPS];
    __shared__ int    fctr[10], bctr[10];
    __shared__ int    bdone, pdone;
    __shared__ float  bstate[130];

    const int b   = blockIdx.x;
    const int tid = threadIdx.x;
    const int w   = tid >> 6;
    const int l   = tid & 63;

    if (tid < 10) { fctr[tid] = 0; bctr[tid] = 0; }
    if (tid == 0) { bdone = 0; pdone = 0; }
    __syncthreads();

    int inlen = in_len[b]; if (inlen < 1) inlen = 1; if (inlen > Tt) inlen = Tt;
    int LLv   = lab_len[b]; if (LLv < 1) LLv = 1; if (LLv > Ll) LLv = Ll;

    const int nct  = (inlen + 7) >> 3;
    const int nchf = nct >> 1;
    const int nchb = nct - nchf;

    const int lab = y_true[b * Ll + l] & 127;
    const float* rowbase = y_pred + (size_t)b * Tt * Cc;

    if (w >= 2) {
        const bool asc = (w < 9);
        const int pw    = asc ? (w - 2) : (w - 9);
        const int nside = asc ? nchf : nchb;
        const int glane = lab >> 1;
        const int lsel  = lab & 1;
        const bool live = (l < LLv);
        int* ctr = asc ? fctr : bctr;
        float acc = 0.0f;

        for (int k = pw, idx = 0; k < nside; k += NPS, ++idx) {
            const int c = asc ? k : (nct - 1 - k);
            const int row0 = c * 8;
            float2 rv[8];
#pragma unroll
            for (int t = 0; t < 8; ++t)
                rv[t] = ((const float2*)(rowbase + (size_t)(row0 + t) * Cc))[l];
            float prod = 1.0f, bsum = 0.0f;
            uint4 pk;
            auto wbits = [&](int t) -> unsigned {
                const float2 v = rv[t];
                float e = fexp2(v.x * INV_LN2) + fexp2(v.y * INV_LN2);
                e = rowsum(e);
                const float s  = (rlf(e, 15) + rlf(e, 31)) + (rlf(e, 47) + rlf(e, 63));
                const float bl = rlf(v.y, 63);
                const bool ok = (row0 + t) < inlen;
                prod *= ok ? s : 1.0f;
                bsum += ok ? bl : 0.0f;
                const float xa = bperm_f(glane, v.x);
                const float xb = bperm_f(glane, v.y);
                const float xl = lsel ? xb : xa;
                float ww = fminf(fmaxf(fexp2((xl - bl) * INV_LN2), 6.1e-5f), 8192.0f);
                ww = live ? ww : 0.0f;
                return (unsigned)__half_as_ushort(__float2half(ww));
            };
            pk.x = wbits(0) | (wbits(1) << 16);
            pk.y = wbits(2) | (wbits(3) << 16);
            pk.z = wbits(4) | (wbits(5) << 16);
            pk.w = wbits(6) | (wbits(7) << 16);
            acc = fmaf(bsum, INV_LN2, acc) - flog2(prod);
            *(uint4*)&w_lds[c][l][0] = pk;
            asm volatile("s_waitcnt lgkmcnt(0)" ::: "memory");
            if (l == 0) atomicAdd(&ctr[idx], 1);
        }
        if (l == 0) ps[(asc ? 0 : NPS) + pw] = acc;
        asm volatile("s_waitcnt lgkmcnt(0)" ::: "memory");
        if (l == 0) atomicAdd(&pdone, 1);
        return;
    }

    const int labp = __shfl_up(lab, 1, 64);
    const float skf = ((l >= 1) && (lab != labp)) ? 1.0f : 0.0f;

    if (w == 1) {
        const float skfb = __shfl(skf, (l + 1) & 63, 64);
        float bE = (l == LLv - 1) ? 1.0f : 0.0f;
        float bO = bE;
        float br = 0.0f, Rb = 0.0f;
        volatile int* vd = bctr;
        int readyd = 0, rrd = 0;
        auto wait_d = [&](int cb) {
            const int needcnt = nct - cb;
            while (readyd < needcnt) {
                const int rem  = nchb - rrd * NPS;
                const int need = rem < NPS ? rem : NPS;
                if (vd[rrd] >= need) { readyd += need; ++rrd; }
                else __builtin_amdgcn_s_sleep(1);
            }
            asm volatile("" ::: "memory");
        };
        if (nchb > 0) {
            wait_d(nct - 1);
            uint4 A = *(const uint4*)&w_lds[nct - 1][l][0];
            for (int cb = nct - 1; cb >= nchf; --cb) {
                uint4 Bv = A;
                if (cb - 1 >= nchf) { wait_d(cb - 1); Bv = *(const uint4*)&w_lds[cb - 1][l][0]; }
                const int t0 = cb * 8;
                if (t0 + 8 <= inlen) do_chunk_b<false>(A, t0, inlen, skfb, bO, bE, br, Rb, l);
                else                 do_chunk_b<true >(A, t0, inlen, skfb, bO, bE, br, Rb, l);
                A = Bv;
            }
        }
        bstate[l]      = bE;
        bstate[64 + l] = bO;
        if (l == 0) { bstate[128] = br; bstate[129] = Rb; }
        asm volatile("s_waitcnt lgkmcnt(0)" ::: "memory");
        if (l == 0) atomicExch(&bdone, 1);
        return;
    }

    float aO = 0.0f, aE = 0.0f, r0 = 1.0f, Rf = 0.0f;
    volatile int* vf = fctr;
    int readyf = 0, rrf = 0;
    auto wait_f = [&](int cneed) {
        while (readyf <= cneed) {
            const int rem  = nchf - rrf * NPS;
            const int need = rem < NPS ? rem : NPS;
            if (vf[rrf] >= need) { readyf += need; ++rrf; }
            else __builtin_amdgcn_s_sleep(1);
        }
        asm volatile("" ::: "memory");
    };
    if (nchf > 0) {
        wait_f(0);
        uint4 A = *(const uint4*)&w_lds[0][l][0];
        for (int c = 0; c < nchf; ++c) {
            uint4 Bv = A;
            if (c + 1 < nchf) { wait_f(c + 1); Bv = *(const uint4*)&w_lds[c + 1][l][0]; }
            do_chunk_f(A, skf, aO, aE, r0, Rf);
            A = Bv;
        }
    }
    {
        volatile int* vp = &pdone;
        while (*vp < 2 * NPS) __builtin_amdgcn_s_sleep(1);
        volatile int* vbd = &bdone;
        while (*vbd == 0) __builtin_amdgcn_s_sleep(1);
        asm volatile("" ::: "memory");
    }
    float cum_b = 0.0f;
#pragma unroll
    for (int q = 0; q < 2 * NPS; ++q) cum_b += ps[q];
    const float bEl = bstate[l], bOl = bstate[64 + l];
    const float br0 = bstate[128], Rb = bstate[129];
    double cd = (double)aE * (double)bEl + (double)aO * (double)bOl;
    if (l == 0) cd += (double)r0 * (double)br0;
#pragma unroll
    for (int mk = 1; mk < 64; mk <<= 1) cd += shflx_d(cd, mk);
    double sd_ = cd > 1e-300 ? cd : 1e-300;
    const long long u = __double_as_longlong(sd_);
    const int e2 = (int)((u >> 52) & 0x7ff) - 1023;
    const double mant = __longlong_as_double((u & 0xfffffffffffffLL) | 0x3ff0000000000000LL);
    const float l2s = (float)e2 + flog2((float)mant);
    if (l == 0)
        out[b] = -LN2_F * (l2s + Rf + Rb + cum_b);
}

extern "C" void kernel_launch(void* const* d_in, const int* in_sizes, int n_in,
                              void* d_out, int out_size, void* d_ws, size_t ws_size,
                              hipStream_t stream) {
    const int*   y_true  = (const int*)d_in[0];    // [256,64]
    const float* y_pred  = (const float*)d_in[1];  // [256,512,128]
    const int*   in_len  = (const int*)d_in[2];    // [256]
    const int*   lab_len = (const int*)d_in[3];    // [256]
    float*       out     = (float*)d_out;          // [256]

    const size_t need = (size_t)256 * 2 * PAYSTRIDE * sizeof(float);  // ~270 KB
    if (d_ws != nullptr && ws_size >= need) {
        float* pay = (float*)d_ws;
        ctc_half_kernel<<<512, 1024, 0, stream>>>(y_true, y_pred, in_len, lab_len, pay);
        ctc_combine_kernel<<<256, 64, 0, stream>>>(pay, out);
    } else {
        ctc_fb_kernel<<<256, 1024, 0, stream>>>(y_true, y_pred, in_len, lab_len, out);
    }
}